// Round 10
// baseline (392.836 us; speedup 1.0000x reference)
//
#include <hip/hip_runtime.h>
#include <hip/hip_bf16.h>

#define NN 100000
#define NE 1000000
#define MPAD 100096   // 782*128
#define MT   782      // m-tiles
#define MTP  784      // padded m-tiles (8*98)

typedef __attribute__((ext_vector_type(8))) short bf16x8;
typedef __attribute__((ext_vector_type(4))) float f32x4;
typedef __attribute__((ext_vector_type(2))) float f32x2;
typedef __attribute__((ext_vector_type(8))) unsigned short us8;

static __device__ __forceinline__ float bf2f(unsigned short u){
  unsigned int x = ((unsigned int)u) << 16;
  return __uint_as_float(x);
}
static __device__ __forceinline__ unsigned short f2bf(float f){
  unsigned int x = __float_as_uint(f);
  unsigned int r = (x + 0x7fffu + ((x >> 16) & 1u)) >> 16;
  return (unsigned short)r;
}
static __device__ __forceinline__ void addv(float* acc, us8 v){
  #pragma unroll
  for (int k = 0; k < 8; k++) acc[k] += bf2f(v[k]);
}
// fp8 e4m3fn encode: RNE, saturate 448, denormals handled (min denorm 2^-9)
static __device__ __forceinline__ unsigned char f2fp8(float f){
  unsigned int u = __float_as_uint(f);
  unsigned int s = (u >> 24) & 0x80u;
  float av = fabsf(f);
  if (av >= 448.f) return (unsigned char)(s | 0x7Eu);
  if (av < 0.015625f){
    int m = (int)(av * 512.0f + 0.5f);
    return (unsigned char)(s | (unsigned)m);
  }
  unsigned int au = u & 0x7FFFFFFFu;
  unsigned int r = au + 0x7FFFFu + ((au >> 20) & 1u);
  return (unsigned char)(s | ((r >> 20) - 960u));
}
#if !__has_builtin(__builtin_amdgcn_cvt_pk_f32_fp8)
static __device__ __forceinline__ float fp8tof(unsigned char b){
  unsigned int s = ((unsigned int)(b & 0x80u)) << 24;
  unsigned int e = (b >> 3) & 0xFu, m = b & 7u;
  float v = (e == 0) ? ((float)m * 0.001953125f)
                     : __uint_as_float(((e + 120u) << 23) | (m << 20));
  return __uint_as_float(__float_as_uint(v) | s);
}
#endif
static __device__ __forceinline__ void addq(float* acc, uint2 v){
#if __has_builtin(__builtin_amdgcn_cvt_pk_f32_fp8)
  f32x2 p0 = __builtin_amdgcn_cvt_pk_f32_fp8((int)v.x, false);
  f32x2 p1 = __builtin_amdgcn_cvt_pk_f32_fp8((int)v.x, true);
  f32x2 p2 = __builtin_amdgcn_cvt_pk_f32_fp8((int)v.y, false);
  f32x2 p3 = __builtin_amdgcn_cvt_pk_f32_fp8((int)v.y, true);
  acc[0] += p0[0]; acc[1] += p0[1]; acc[2] += p1[0]; acc[3] += p1[1];
  acc[4] += p2[0]; acc[5] += p2[1]; acc[6] += p3[0]; acc[7] += p3[1];
#else
  unsigned int a = v.x, b = v.y;
  acc[0] += fp8tof(a & 0xFF);         acc[1] += fp8tof((a >> 8) & 0xFF);
  acc[2] += fp8tof((a >> 16) & 0xFF); acc[3] += fp8tof(a >> 24);
  acc[4] += fp8tof(b & 0xFF);         acc[5] += fp8tof((b >> 8) & 0xFF);
  acc[6] += fp8tof((b >> 16) & 0xFF); acc[7] += fp8tof(b >> 24);
#endif
}
static __device__ __forceinline__ void gld16(const void* g, void* l){
  __builtin_amdgcn_global_load_lds((const __attribute__((address_space(1))) void*)g,
                                   (__attribute__((address_space(3))) void*)l, 16, 0, 0);
}

// ---------------- CSR build ----------------

__global__ void k_degree(const int* __restrict__ dst, int* __restrict__ cnt, int E){
  int e = blockIdx.x * blockDim.x + threadIdx.x;
  if (e < E) atomicAdd(&cnt[dst[e]], 1);
}

__global__ void k_chunk_sum(const int* __restrict__ cnt, int* __restrict__ partials, int N){
  __shared__ int sw[16];
  int b = blockIdx.x, t = threadIdx.x;
  int i = b * 1024 + t;
  int v = (i < N) ? cnt[i] : 0;
  #pragma unroll
  for (int off = 32; off; off >>= 1) v += __shfl_xor(v, off);
  int lane = t & 63, w = t >> 6;
  if (lane == 0) sw[w] = v;
  __syncthreads();
  if (t < 16){
    int s = sw[t];
    #pragma unroll
    for (int off = 8; off; off >>= 1) s += __shfl_xor(s, off);
    if (t == 0) partials[b] = s;
  }
}

__global__ void k_chunk_scan(const int* __restrict__ cnt, const int* __restrict__ partials,
                             int nchunk,
                             int* __restrict__ offs, int* __restrict__ cursor,
                             float* __restrict__ deginv, int N){
  __shared__ int sd[1024];
  __shared__ int sp[128];
  int b = blockIdx.x, t = threadIdx.x;
  if (t < 128) sp[t] = (t < b && t < nchunk) ? partials[t] : 0;
  int i = b * 1024 + t;
  int v = (i < N) ? cnt[i] : 0;
  sd[t] = v;
  __syncthreads();
  #pragma unroll
  for (int off = 64; off; off >>= 1){
    if (t < off) sp[t] += sp[t + off];
    __syncthreads();
  }
  for (int off = 1; off < 1024; off <<= 1){
    int x = (t >= off) ? sd[t - off] : 0;
    __syncthreads();
    sd[t] += x;
    __syncthreads();
  }
  if (i < N){
    int excl = sp[0] + sd[t] - v;
    offs[i] = excl;
    cursor[i] = excl;
    deginv[i] = (v > 0) ? (1.0f / (float)v) : 0.0f;
  }
}

__global__ void k_fill(const int* __restrict__ src, const int* __restrict__ dst,
                       int* __restrict__ cursor, int* __restrict__ csr, int E){
  int e = blockIdx.x * blockDim.x + threadIdx.x;
  if (e < E){
    int p = atomicAdd(&cursor[dst[e]], 1);
    csr[p] = src[e];
  }
}

// ---------------- input cast + pad: x f32 -> xb bf16 [MPAD][256] ----------------

__global__ void k_cvt(const float* __restrict__ x, unsigned short* __restrict__ xb){
  size_t i = ((size_t)blockIdx.x * 256 + threadIdx.x) * 8;
  if (i >= (size_t)MPAD * 256) return;
  int row = (int)(i >> 8);
  us8 o;
  if (row < NN){
    const float4* p = (const float4*)(x + i);
    float4 a = p[0], b = p[1];
    o[0]=f2bf(a.x); o[1]=f2bf(a.y); o[2]=f2bf(a.z); o[3]=f2bf(a.w);
    o[4]=f2bf(b.x); o[5]=f2bf(b.y); o[6]=f2bf(b.z); o[7]=f2bf(b.w);
  } else {
    #pragma unroll
    for (int j = 0; j < 8; j++) o[j] = 0;
  }
  *(us8*)(xb + i) = o;
}

// ---------------- weight prep ----------------

__global__ void k_prep_w(const float* __restrict__ W1l, const float* __restrict__ W1r,
                         const float* __restrict__ W2l, const float* __restrict__ W2r,
                         unsigned short* __restrict__ Bt1, unsigned short* __restrict__ Bt2){
  int i = blockIdx.x * 256 + threadIdx.x;
  if (i < 512 * 256){
    int n = i >> 8, k = i & 255;
    float v = (n < 256) ? W1l[k * 256 + n] : W1r[k * 256 + (n - 256)];
    Bt1[n * 256 + k] = f2bf(v);
  }
  if (i < 256 * 256){
    int n = i >> 8, k = i & 255;
    float v = (n < 128) ? W2l[k * 128 + n] : W2r[k * 128 + (n - 128)];
    Bt2[n * 256 + k] = f2bf(v);
  }
}

// ---------------- MFMA GEMM (XCD-pinned 1D grid, A in LDS, B in registers) ----
// B panels are tiny (<=256KB) and L2-resident per XCD: load B fragments
// directly to VGPRs each K-step; only A is staged via global_load_lds.
// LDS halves to 16KB -> more resident blocks; B latency hides under A DMA.
// SPLIT=true (layer 1): cols 0..255 -> Q8 fp8 [MPAD][256], cols 256..511 -> C bf16 [MPAD][256]

template<int NTL2, bool SPLIT>
__global__ __launch_bounds__(256)
void k_gemm(const unsigned short* __restrict__ A,
            const unsigned short* __restrict__ Bt,
            unsigned short* __restrict__ C,
            unsigned char* __restrict__ Q8)
{
  const int bid = blockIdx.x;
  const int xcd = bid & 7, j = bid >> 3;
  const int mt  = xcd * (MTP / 8) + (j >> NTL2);
  if (mt >= MT) return;
  const int nt  = j & ((1 << NTL2) - 1);
  const int m0  = mt * 128;
  const int n0  = nt * 128;
  const int Nout = 128 << NTL2;

  __shared__ __align__(16) unsigned short lA[128 * 64];   // 16KB
  const int t = threadIdx.x;
  const int lane = t & 63, wid = t >> 6;
  const int wm = wid >> 1, wn = wid & 1;

  f32x4 acc[4][4] = {};

  const int strow = wid * 32 + (lane >> 3);
  const int sc    = (lane & 7) ^ ((lane >> 3) & 7);
  // per-wave B base: row (col of C) = n0 + wn*64 + n*16 + (lane&15); k-chunk (lane>>4)
  const unsigned short* bbase = Bt + (size_t)(n0 + wn * 64 + (lane & 15)) * 256 + (lane >> 4) * 8;

  for (int kt = 0; kt < 4; ++kt){
    __syncthreads();
    #pragma unroll
    for (int s4 = 0; s4 < 4; ++s4){
      int row = strow + s4 * 8;
      gld16(A + (size_t)(m0 + row) * 256 + kt * 64 + sc * 8, &lA[(wid * 4 + s4) * 512]);
    }
    // B fragments for this K-step -> registers (overlaps with A DMA)
    bf16x8 bv0[4], bv1[4];
    #pragma unroll
    for (int n = 0; n < 4; n++){
      const unsigned short* bp = bbase + (size_t)(n * 16) * 256 + kt * 64;
      bv0[n] = *(const bf16x8*)bp;          // ks=0: k = kt*64 + (lane>>4)*8
      bv1[n] = *(const bf16x8*)(bp + 32);   // ks=1: +32 elems (4 chunks)
    }
    __syncthreads();   // waits vmcnt(0): lA ready, bv ready
    {
      bf16x8 av[4];
      const int kc0 = (lane >> 4);
      #pragma unroll
      for (int m = 0; m < 4; m++){
        int r = wm * 64 + m * 16 + (lane & 15);
        av[m] = *(const bf16x8*)&lA[r * 64 + ((kc0 ^ (r & 7)) << 3)];
      }
      #pragma unroll
      for (int m = 0; m < 4; m++)
        #pragma unroll
        for (int n = 0; n < 4; n++)
          acc[m][n] = __builtin_amdgcn_mfma_f32_16x16x32_bf16(av[m], bv0[n], acc[m][n], 0, 0, 0);
    }
    {
      bf16x8 av[4];
      const int kc1 = 4 + (lane >> 4);
      #pragma unroll
      for (int m = 0; m < 4; m++){
        int r = wm * 64 + m * 16 + (lane & 15);
        av[m] = *(const bf16x8*)&lA[r * 64 + ((kc1 ^ (r & 7)) << 3)];
      }
      #pragma unroll
      for (int m = 0; m < 4; m++)
        #pragma unroll
        for (int n = 0; n < 4; n++)
          acc[m][n] = __builtin_amdgcn_mfma_f32_16x16x32_bf16(av[m], bv1[n], acc[m][n], 0, 0, 0);
    }
  }

  const int crow0 = m0 + wm * 64 + (lane >> 4) * 4;
  const int ccol0 = n0 + wn * 64 + (lane & 15);
  if (SPLIT && n0 < 256){
    #pragma unroll
    for (int m = 0; m < 4; m++){
      #pragma unroll
      for (int r = 0; r < 4; r++){
        size_t rowoff = (size_t)(crow0 + m * 16 + r) * 256;
        #pragma unroll
        for (int n = 0; n < 4; n++)
          Q8[rowoff + ccol0 + n * 16] = f2fp8(acc[m][n][r]);
      }
    }
  } else {
    const int stride = SPLIT ? 256 : Nout;
    const int cbase  = SPLIT ? (ccol0 - 256) : ccol0;
    #pragma unroll
    for (int m = 0; m < 4; m++){
      #pragma unroll
      for (int r = 0; r < 4; r++){
        size_t rowoff = (size_t)(crow0 + m * 16 + r) * stride;
        #pragma unroll
        for (int n = 0; n < 4; n++)
          C[rowoff + cbase + n * 16] = f2bf(acc[m][n][r]);
      }
    }
  }
}

// ---------------- Aggregation 1: h = relu(deginv*agg(q1_fp8) + r1 + b1) ----------------

__global__ void k_agg1(const unsigned char* __restrict__ Q8,
                       const unsigned short* __restrict__ R1,
                       const float* __restrict__ b1,
                       const int* __restrict__ offs, const int* __restrict__ cnt,
                       const float* __restrict__ deginv,
                       const int* __restrict__ csr,
                       unsigned short* __restrict__ h, int N)
{
  int wv = threadIdx.x >> 6, lane = threadIdx.x & 63;
  int n = blockIdx.x * 4 + wv;
  if (n >= N) return;
  int beg = offs[n], d = cnt[n];
  const int g = lane >> 5;       // edge-group 0/1
  const int cl = lane & 31;      // cols cl*8..cl*8+7
  const unsigned char* Qb = Q8 + cl * 8;

  float acc[8];
  #pragma unroll
  for (int k = 0; k < 8; k++) acc[k] = 0.f;

  for (int w0 = 0; w0 < d; w0 += 64){
    int wlen = min(d - w0, 64);
    int idx = 0;
    if (lane < wlen) idx = csr[beg + w0 + lane];
    int nIter = (wlen + 15) >> 4;              // uniform across the wave
    for (int t = 0; t < nIter; t++){
      int e0 = t * 16 + g;
      int s0 = __shfl(idx, e0);
      int s1 = __shfl(idx, e0 + 2);
      int s2 = __shfl(idx, e0 + 4);
      int s3 = __shfl(idx, e0 + 6);
      int s4 = __shfl(idx, e0 + 8);
      int s5 = __shfl(idx, e0 + 10);
      int s6 = __shfl(idx, e0 + 12);
      int s7 = __shfl(idx, e0 + 14);
      uint2 v0 = *(const uint2*)(Qb + (size_t)s0 * 256);
      uint2 v1 = *(const uint2*)(Qb + (size_t)s1 * 256);
      uint2 v2 = *(const uint2*)(Qb + (size_t)s2 * 256);
      uint2 v3 = *(const uint2*)(Qb + (size_t)s3 * 256);
      uint2 v4 = *(const uint2*)(Qb + (size_t)s4 * 256);
      uint2 v5 = *(const uint2*)(Qb + (size_t)s5 * 256);
      uint2 v6 = *(const uint2*)(Qb + (size_t)s6 * 256);
      uint2 v7 = *(const uint2*)(Qb + (size_t)s7 * 256);
      if (e0 < wlen)      addq(acc, v0);
      if (e0 + 2 < wlen)  addq(acc, v1);
      if (e0 + 4 < wlen)  addq(acc, v2);
      if (e0 + 6 < wlen)  addq(acc, v3);
      if (e0 + 8 < wlen)  addq(acc, v4);
      if (e0 + 10 < wlen) addq(acc, v5);
      if (e0 + 12 < wlen) addq(acc, v6);
      if (e0 + 14 < wlen) addq(acc, v7);
    }
  }
  #pragma unroll
  for (int k = 0; k < 8; k++) acc[k] += __shfl_xor(acc[k], 32);

  if (lane < 32){
    float di = deginv[n];
    us8 rv = *(const us8*)(R1 + (size_t)n * 256 + cl * 8);
    float4 b0 = *(const float4*)(b1 + cl * 8);
    float4 b4 = *(const float4*)(b1 + cl * 8 + 4);
    float bb[8] = {b0.x, b0.y, b0.z, b0.w, b4.x, b4.y, b4.z, b4.w};
    us8 o;
    #pragma unroll
    for (int k = 0; k < 8; k++)
      o[k] = f2bf(fmaxf(acc[k] * di + bf2f(rv[k]) + bb[k], 0.f));
    *(us8*)(h + (size_t)n * 256 + cl * 8) = o;
  }
}

// ---------------- Aggregation 2 + classifier + log_softmax (fused, bf16) ----------------

__global__ void k_agg2cls(const unsigned short* __restrict__ C2,
                          const float* __restrict__ b2,
                          const float* __restrict__ Wc,
                          const float* __restrict__ bc,
                          const int* __restrict__ offs, const int* __restrict__ cnt,
                          const float* __restrict__ deginv,
                          const int* __restrict__ csr,
                          float* __restrict__ out, int N)
{
  int wv = threadIdx.x >> 6, lane = threadIdx.x & 63;
  int n = blockIdx.x * 4 + wv;
  if (n >= N) return;
  int beg = offs[n], d = cnt[n];
  const int g = lane >> 4;       // edge-group 0..3
  const int cl = lane & 15;      // cols cl*8..cl*8+7

  float acc[8];
  #pragma unroll
  for (int k = 0; k < 8; k++) acc[k] = 0.f;

  for (int w0 = 0; w0 < d; w0 += 64){
    int wlen = min(d - w0, 64);
    int idx = 0;
    if (lane < wlen) idx = csr[beg + w0 + lane];
    int nIter = (wlen + 31) >> 5;              // uniform across the wave
    for (int t = 0; t < nIter; t++){
      int e0 = t * 32 + g;
      int s0 = __shfl(idx, e0);
      int s1 = __shfl(idx, e0 + 4);
      int s2 = __shfl(idx, e0 + 8);
      int s3 = __shfl(idx, e0 + 12);
      int s4 = __shfl(idx, e0 + 16);
      int s5 = __shfl(idx, e0 + 20);
      int s6 = __shfl(idx, e0 + 24);
      int s7 = __shfl(idx, e0 + 28);
      us8 v0 = *(const us8*)(C2 + (size_t)s0 * 256 + cl * 8);
      us8 v1 = *(const us8*)(C2 + (size_t)s1 * 256 + cl * 8);
      us8 v2 = *(const us8*)(C2 + (size_t)s2 * 256 + cl * 8);
      us8 v3 = *(const us8*)(C2 + (size_t)s3 * 256 + cl * 8);
      us8 v4 = *(const us8*)(C2 + (size_t)s4 * 256 + cl * 8);
      us8 v5 = *(const us8*)(C2 + (size_t)s5 * 256 + cl * 8);
      us8 v6 = *(const us8*)(C2 + (size_t)s6 * 256 + cl * 8);
      us8 v7 = *(const us8*)(C2 + (size_t)s7 * 256 + cl * 8);
      if (e0 < wlen)      addv(acc, v0);
      if (e0 + 4 < wlen)  addv(acc, v1);
      if (e0 + 8 < wlen)  addv(acc, v2);
      if (e0 + 12 < wlen) addv(acc, v3);
      if (e0 + 16 < wlen) addv(acc, v4);
      if (e0 + 20 < wlen) addv(acc, v5);
      if (e0 + 24 < wlen) addv(acc, v6);
      if (e0 + 28 < wlen) addv(acc, v7);
    }
  }
  #pragma unroll
  for (int k = 0; k < 8; k++){
    acc[k] += __shfl_xor(acc[k], 16);
    acc[k] += __shfl_xor(acc[k], 32);
  }

  float di = deginv[n];
  us8 rv = *(const us8*)(C2 + (size_t)n * 256 + 128 + cl * 8);
  float4 b0 = *(const float4*)(b2 + cl * 8);
  float4 b4 = *(const float4*)(b2 + cl * 8 + 4);
  float bb[8] = {b0.x, b0.y, b0.z, b0.w, b4.x, b4.y, b4.z, b4.w};
  float p0 = 0.f, p1 = 0.f;
  #pragma unroll
  for (int k = 0; k < 8; k += 2){
    float h0 = fmaxf(acc[k]     * di + bf2f(rv[k])     + bb[k],     0.f);
    float h1 = fmaxf(acc[k + 1] * di + bf2f(rv[k + 1]) + bb[k + 1], 0.f);
    float4 w = *(const float4*)(Wc + (cl * 8 + k) * 2);
    p0 += h0 * w.x + h1 * w.z;
    p1 += h0 * w.y + h1 * w.w;
  }
  #pragma unroll
  for (int off = 8; off; off >>= 1){
    p0 += __shfl_xor(p0, off);
    p1 += __shfl_xor(p1, off);
  }
  if (lane == 0){
    float z0 = p0 + bc[0], z1 = p1 + bc[1];
    float m = fmaxf(z0, z1);
    float lse = m + logf(expf(z0 - m) + expf(z1 - m));
    out[(size_t)n * 2 + 0] = z0 - lse;
    out[(size_t)n * 2 + 1] = z1 - lse;
  }
}

// ---------------- host launch ----------------

extern "C" void kernel_launch(void* const* d_in, const int* in_sizes, int n_in,
                              void* d_out, int out_size, void* d_ws, size_t ws_size,
                              hipStream_t stream)
{
  const float* x   = (const float*)d_in[0];
  const int*   ei  = (const int*)d_in[1];
  const float* W1l = (const float*)d_in[2];
  const float* W1r = (const float*)d_in[3];
  const float* b1  = (const float*)d_in[4];
  const float* W2l = (const float*)d_in[5];
  const float* W2r = (const float*)d_in[6];
  const float* b2  = (const float*)d_in[7];
  const float* Wc  = (const float*)d_in[8];
  const float* bc  = (const float*)d_in[9];
  float* out = (float*)d_out;

  const int N = NN, E = NE;
  const int* src = ei;
  const int* dst = ei + E;

  char* ws = (char*)d_ws;
  size_t off = 0;
  auto alloc = [&](size_t bytes) -> void* {
    void* p = ws + off;
    off += (bytes + 255) & ~(size_t)255;
    return p;
  };
  int*   cnt      = (int*)alloc((size_t)N * 4);
  int*   offs     = (int*)alloc((size_t)N * 4);
  int*   cursor   = (int*)alloc((size_t)N * 4);
  float* deginv   = (float*)alloc((size_t)N * 4);
  int*   partials = (int*)alloc(1024);
  int*   csr      = (int*)alloc((size_t)E * 4);
  unsigned short* Bt1 = (unsigned short*)alloc((size_t)512 * 256 * 2);
  unsigned short* Bt2 = (unsigned short*)alloc((size_t)256 * 256 * 2);
  unsigned short* xb  = (unsigned short*)alloc((size_t)MPAD * 256 * 2);
  unsigned char*  Q8  = (unsigned char*)alloc((size_t)MPAD * 256);
  unsigned short* R1  = (unsigned short*)alloc((size_t)MPAD * 256 * 2);

  unsigned short* h  = xb;   // alias: xb dead after gemm1
  unsigned short* C2 = R1;   // alias: R1 dead after agg1

  (void)in_sizes; (void)n_in; (void)out_size; (void)ws_size;

  hipMemsetAsync(cnt, 0, (size_t)N * 4, stream);

  int nchunk = (N + 1023) / 1024;
  k_degree<<<(E + 255) / 256, 256, 0, stream>>>(dst, cnt, E);
  k_chunk_sum<<<nchunk, 1024, 0, stream>>>(cnt, partials, N);
  k_chunk_scan<<<nchunk, 1024, 0, stream>>>(cnt, partials, nchunk, offs, cursor, deginv, N);
  k_fill<<<(E + 255) / 256, 256, 0, stream>>>(src, dst, cursor, csr, E);

  k_cvt<<<MPAD / 8, 256, 0, stream>>>(x, xb);
  k_prep_w<<<512, 256, 0, stream>>>(W1l, W1r, W2l, W2r, Bt1, Bt2);

  // layer 1: [q1|r1] = xb @ [W1l|W1r]; q1 -> Q8 fp8 [MPAD][256], r1 -> R1 bf16
  k_gemm<2, true><<<MTP * 4, 256, 0, stream>>>(xb, Bt1, R1, Q8);
  k_agg1<<<N / 4, 256, 0, stream>>>(Q8, R1, b1, offs, cnt, deginv, csr, h, N);

  // layer 2: C2 = h @ [W2l|W2r]
  k_gemm<1, false><<<MTP * 2, 256, 0, stream>>>(h, Bt2, C2, (unsigned char*)nullptr);
  // agg2 + classifier + log_softmax fused
  k_agg2cls<<<N / 4, 256, 0, stream>>>(C2, b2, Wc, bc, offs, cnt, deginv, csr, out, N);
}

// Round 11
// 348.963 us; speedup vs baseline: 1.1257x; 1.1257x over previous
//
#include <hip/hip_runtime.h>
#include <hip/hip_bf16.h>

#define NN 100000
#define NE 1000000
#define MPAD 100096   // 1564*64
#define MT64  1564    // 64-row m-tiles
#define MTP64 1568    // padded (8*196)

typedef __attribute__((ext_vector_type(8))) short bf16x8;
typedef __attribute__((ext_vector_type(4))) float f32x4;
typedef __attribute__((ext_vector_type(2))) float f32x2;
typedef __attribute__((ext_vector_type(8))) unsigned short us8;

static __device__ __forceinline__ float bf2f(unsigned short u){
  unsigned int x = ((unsigned int)u) << 16;
  return __uint_as_float(x);
}
static __device__ __forceinline__ unsigned short f2bf(float f){
  unsigned int x = __float_as_uint(f);
  unsigned int r = (x + 0x7fffu + ((x >> 16) & 1u)) >> 16;
  return (unsigned short)r;
}
static __device__ __forceinline__ void addv(float* acc, us8 v){
  #pragma unroll
  for (int k = 0; k < 8; k++) acc[k] += bf2f(v[k]);
}
// fp8 e4m3fn encode: RNE, saturate 448, denormals handled
static __device__ __forceinline__ unsigned char f2fp8(float f){
  unsigned int u = __float_as_uint(f);
  unsigned int s = (u >> 24) & 0x80u;
  float av = fabsf(f);
  if (av >= 448.f) return (unsigned char)(s | 0x7Eu);
  if (av < 0.015625f){
    int m = (int)(av * 512.0f + 0.5f);
    return (unsigned char)(s | (unsigned)m);
  }
  unsigned int au = u & 0x7FFFFFFFu;
  unsigned int r = au + 0x7FFFFu + ((au >> 20) & 1u);
  return (unsigned char)(s | ((r >> 20) - 960u));
}
#if !__has_builtin(__builtin_amdgcn_cvt_pk_f32_fp8)
static __device__ __forceinline__ float fp8tof(unsigned char b){
  unsigned int s = ((unsigned int)(b & 0x80u)) << 24;
  unsigned int e = (b >> 3) & 0xFu, m = b & 7u;
  float v = (e == 0) ? ((float)m * 0.001953125f)
                     : __uint_as_float(((e + 120u) << 23) | (m << 20));
  return __uint_as_float(__float_as_uint(v) | s);
}
#endif
static __device__ __forceinline__ void addq(float* acc, uint2 v){
#if __has_builtin(__builtin_amdgcn_cvt_pk_f32_fp8)
  f32x2 p0 = __builtin_amdgcn_cvt_pk_f32_fp8((int)v.x, false);
  f32x2 p1 = __builtin_amdgcn_cvt_pk_f32_fp8((int)v.x, true);
  f32x2 p2 = __builtin_amdgcn_cvt_pk_f32_fp8((int)v.y, false);
  f32x2 p3 = __builtin_amdgcn_cvt_pk_f32_fp8((int)v.y, true);
  acc[0] += p0[0]; acc[1] += p0[1]; acc[2] += p1[0]; acc[3] += p1[1];
  acc[4] += p2[0]; acc[5] += p2[1]; acc[6] += p3[0]; acc[7] += p3[1];
#else
  unsigned int a = v.x, b = v.y;
  acc[0] += fp8tof(a & 0xFF);         acc[1] += fp8tof((a >> 8) & 0xFF);
  acc[2] += fp8tof((a >> 16) & 0xFF); acc[3] += fp8tof(a >> 24);
  acc[4] += fp8tof(b & 0xFF);         acc[5] += fp8tof((b >> 8) & 0xFF);
  acc[6] += fp8tof((b >> 16) & 0xFF); acc[7] += fp8tof(b >> 24);
#endif
}
static __device__ __forceinline__ void gld16(const void* g, void* l){
  __builtin_amdgcn_global_load_lds((const __attribute__((address_space(1))) void*)g,
                                   (__attribute__((address_space(3))) void*)l, 16, 0, 0);
}

// ---------------- CSR build ----------------

__global__ void k_degree(const int* __restrict__ dst, int* __restrict__ cnt, int E){
  int e = blockIdx.x * blockDim.x + threadIdx.x;
  if (e < E) atomicAdd(&cnt[dst[e]], 1);
}

__global__ void k_chunk_sum(const int* __restrict__ cnt, int* __restrict__ partials, int N){
  __shared__ int sw[16];
  int b = blockIdx.x, t = threadIdx.x;
  int i = b * 1024 + t;
  int v = (i < N) ? cnt[i] : 0;
  #pragma unroll
  for (int off = 32; off; off >>= 1) v += __shfl_xor(v, off);
  int lane = t & 63, w = t >> 6;
  if (lane == 0) sw[w] = v;
  __syncthreads();
  if (t < 16){
    int s = sw[t];
    #pragma unroll
    for (int off = 8; off; off >>= 1) s += __shfl_xor(s, off);
    if (t == 0) partials[b] = s;
  }
}

__global__ void k_chunk_scan(const int* __restrict__ cnt, const int* __restrict__ partials,
                             int nchunk,
                             int* __restrict__ offs, int* __restrict__ cursor,
                             float* __restrict__ deginv, int N){
  __shared__ int sd[1024];
  __shared__ int sp[128];
  int b = blockIdx.x, t = threadIdx.x;
  if (t < 128) sp[t] = (t < b && t < nchunk) ? partials[t] : 0;
  int i = b * 1024 + t;
  int v = (i < N) ? cnt[i] : 0;
  sd[t] = v;
  __syncthreads();
  #pragma unroll
  for (int off = 64; off; off >>= 1){
    if (t < off) sp[t] += sp[t + off];
    __syncthreads();
  }
  for (int off = 1; off < 1024; off <<= 1){
    int x = (t >= off) ? sd[t - off] : 0;
    __syncthreads();
    sd[t] += x;
    __syncthreads();
  }
  if (i < N){
    int excl = sp[0] + sd[t] - v;
    offs[i] = excl;
    cursor[i] = excl;
    deginv[i] = (v > 0) ? (1.0f / (float)v) : 0.0f;
  }
}

__global__ void k_fill(const int* __restrict__ src, const int* __restrict__ dst,
                       int* __restrict__ cursor, int* __restrict__ csr, int E){
  int e = blockIdx.x * blockDim.x + threadIdx.x;
  if (e < E){
    int p = atomicAdd(&cursor[dst[e]], 1);
    csr[p] = src[e];
  }
}

// ---------------- input cast + pad: x f32 -> xb bf16 [MPAD][256] ----------------

__global__ void k_cvt(const float* __restrict__ x, unsigned short* __restrict__ xb){
  size_t i = ((size_t)blockIdx.x * 256 + threadIdx.x) * 8;
  if (i >= (size_t)MPAD * 256) return;
  int row = (int)(i >> 8);
  us8 o;
  if (row < NN){
    const float4* p = (const float4*)(x + i);
    float4 a = p[0], b = p[1];
    o[0]=f2bf(a.x); o[1]=f2bf(a.y); o[2]=f2bf(a.z); o[3]=f2bf(a.w);
    o[4]=f2bf(b.x); o[5]=f2bf(b.y); o[6]=f2bf(b.z); o[7]=f2bf(b.w);
  } else {
    #pragma unroll
    for (int j = 0; j < 8; j++) o[j] = 0;
  }
  *(us8*)(xb + i) = o;
}

// ---------------- weight prep ----------------

__global__ void k_prep_w(const float* __restrict__ W1l, const float* __restrict__ W1r,
                         const float* __restrict__ W2l, const float* __restrict__ W2r,
                         unsigned short* __restrict__ Bt1, unsigned short* __restrict__ Bt2){
  int i = blockIdx.x * 256 + threadIdx.x;
  if (i < 512 * 256){
    int n = i >> 8, k = i & 255;
    float v = (n < 256) ? W1l[k * 256 + n] : W1r[k * 256 + (n - 256)];
    Bt1[n * 256 + k] = f2bf(v);
  }
  if (i < 256 * 256){
    int n = i >> 8, k = i & 255;
    float v = (n < 128) ? W2l[k * 128 + n] : W2r[k * 128 + (n - 128)];
    Bt2[n * 256 + k] = f2bf(v);
  }
}

// ---------------- Barrier-free single-wave MFMA GEMM ----------------
// One wave per 64x64 C-tile. Per-wave LDS staging via global_load_lds;
// synchronization = explicit s_waitcnt only (no __syncthreads). 16KB LDS
// per block -> ~10 independent waves/CU; their phases interleave so DMA
// latency hides under other waves' MFMA.
// XCD-pinned: bid&7 -> XCD; all n-tiles of an m-tile on same XCD (A L2-hit).
// SPLIT=true (layer 1, Nout=512): cols<256 -> Q8 fp8 [MPAD][256], else C bf16 [MPAD][256].

template<int NTL2, bool SPLIT>
__global__ __launch_bounds__(64)
void k_gemm(const unsigned short* __restrict__ A,
            const unsigned short* __restrict__ Bt,
            unsigned short* __restrict__ C,
            unsigned char* __restrict__ Q8)
{
  const int bid = blockIdx.x;
  const int xcd = bid & 7, j = bid >> 3;
  const int mt  = xcd * (MTP64 / 8) + (j >> NTL2);
  if (mt >= MT64) return;
  const int nt  = j & ((1 << NTL2) - 1);
  const int m0  = mt * 64;
  const int n0  = nt * 64;
  const int Nout = 64 << NTL2;

  __shared__ __align__(16) unsigned short lA[64 * 64];  // 8KB
  __shared__ __align__(16) unsigned short lB[64 * 64];  // 8KB
  const int lane = threadIdx.x & 63;

  f32x4 acc[4][4] = {};

  const int srow = lane >> 3;                         // + s*8
  const int sc   = (lane & 7) ^ ((lane >> 3) & 7);    // swizzled source chunk

  for (int kt = 0; kt < 4; ++kt){
    // prior ds_reads must complete before overwriting LDS (no-op on kt=0)
    asm volatile("s_waitcnt lgkmcnt(0)" ::: "memory");
    #pragma unroll
    for (int s = 0; s < 8; ++s){
      int row = s * 8 + srow;
      gld16(A  + (size_t)(m0 + row) * 256 + kt * 64 + sc * 8, &lA[s * 512]);
      gld16(Bt + (size_t)(n0 + row) * 256 + kt * 64 + sc * 8, &lB[s * 512]);
    }
    asm volatile("s_waitcnt vmcnt(0)" ::: "memory");  // wave's own DMA landed
    __builtin_amdgcn_sched_barrier(0);
    #pragma unroll
    for (int ks = 0; ks < 2; ++ks){
      bf16x8 av[4], bv[4];
      const int kc = ks * 4 + (lane >> 4);
      #pragma unroll
      for (int m = 0; m < 4; m++){
        int r = m * 16 + (lane & 15);
        av[m] = *(const bf16x8*)&lA[r * 64 + ((kc ^ (r & 7)) << 3)];
      }
      #pragma unroll
      for (int n = 0; n < 4; n++){
        int c = n * 16 + (lane & 15);
        bv[n] = *(const bf16x8*)&lB[c * 64 + ((kc ^ (c & 7)) << 3)];
      }
      #pragma unroll
      for (int m = 0; m < 4; m++)
        #pragma unroll
        for (int n = 0; n < 4; n++)
          acc[m][n] = __builtin_amdgcn_mfma_f32_16x16x32_bf16(av[m], bv[n], acc[m][n], 0, 0, 0);
    }
  }

  const int crow0 = m0 + (lane >> 4) * 4;
  const int ccol0 = n0 + (lane & 15);
  if (SPLIT && n0 < 256){
    #pragma unroll
    for (int m = 0; m < 4; m++){
      #pragma unroll
      for (int r = 0; r < 4; r++){
        size_t rowoff = (size_t)(crow0 + m * 16 + r) * 256;
        #pragma unroll
        for (int n = 0; n < 4; n++)
          Q8[rowoff + ccol0 + n * 16] = f2fp8(acc[m][n][r]);
      }
    }
  } else {
    const int stride = SPLIT ? 256 : Nout;
    const int cbase  = SPLIT ? (ccol0 - 256) : ccol0;
    #pragma unroll
    for (int m = 0; m < 4; m++){
      #pragma unroll
      for (int r = 0; r < 4; r++){
        size_t rowoff = (size_t)(crow0 + m * 16 + r) * stride;
        #pragma unroll
        for (int n = 0; n < 4; n++)
          C[rowoff + cbase + n * 16] = f2bf(acc[m][n][r]);
      }
    }
  }
}

// ---------------- Aggregation 1: h = relu(deginv*agg(q1_fp8) + r1 + b1) ----------------

__global__ void k_agg1(const unsigned char* __restrict__ Q8,
                       const unsigned short* __restrict__ R1,
                       const float* __restrict__ b1,
                       const int* __restrict__ offs, const int* __restrict__ cnt,
                       const float* __restrict__ deginv,
                       const int* __restrict__ csr,
                       unsigned short* __restrict__ h, int N)
{
  int wv = threadIdx.x >> 6, lane = threadIdx.x & 63;
  int n = blockIdx.x * 4 + wv;
  if (n >= N) return;
  int beg = offs[n], d = cnt[n];
  const int g = lane >> 5;       // edge-group 0/1
  const int cl = lane & 31;      // cols cl*8..cl*8+7
  const unsigned char* Qb = Q8 + cl * 8;

  float acc[8];
  #pragma unroll
  for (int k = 0; k < 8; k++) acc[k] = 0.f;

  for (int w0 = 0; w0 < d; w0 += 64){
    int wlen = min(d - w0, 64);
    int idx = 0;
    if (lane < wlen) idx = csr[beg + w0 + lane];
    int nIter = (wlen + 15) >> 4;              // uniform across the wave
    for (int t = 0; t < nIter; t++){
      int e0 = t * 16 + g;
      int s0 = __shfl(idx, e0);
      int s1 = __shfl(idx, e0 + 2);
      int s2 = __shfl(idx, e0 + 4);
      int s3 = __shfl(idx, e0 + 6);
      int s4 = __shfl(idx, e0 + 8);
      int s5 = __shfl(idx, e0 + 10);
      int s6 = __shfl(idx, e0 + 12);
      int s7 = __shfl(idx, e0 + 14);
      uint2 v0 = *(const uint2*)(Qb + (size_t)s0 * 256);
      uint2 v1 = *(const uint2*)(Qb + (size_t)s1 * 256);
      uint2 v2 = *(const uint2*)(Qb + (size_t)s2 * 256);
      uint2 v3 = *(const uint2*)(Qb + (size_t)s3 * 256);
      uint2 v4 = *(const uint2*)(Qb + (size_t)s4 * 256);
      uint2 v5 = *(const uint2*)(Qb + (size_t)s5 * 256);
      uint2 v6 = *(const uint2*)(Qb + (size_t)s6 * 256);
      uint2 v7 = *(const uint2*)(Qb + (size_t)s7 * 256);
      if (e0 < wlen)      addq(acc, v0);
      if (e0 + 2 < wlen)  addq(acc, v1);
      if (e0 + 4 < wlen)  addq(acc, v2);
      if (e0 + 6 < wlen)  addq(acc, v3);
      if (e0 + 8 < wlen)  addq(acc, v4);
      if (e0 + 10 < wlen) addq(acc, v5);
      if (e0 + 12 < wlen) addq(acc, v6);
      if (e0 + 14 < wlen) addq(acc, v7);
    }
  }
  #pragma unroll
  for (int k = 0; k < 8; k++) acc[k] += __shfl_xor(acc[k], 32);

  if (lane < 32){
    float di = deginv[n];
    us8 rv = *(const us8*)(R1 + (size_t)n * 256 + cl * 8);
    float4 b0 = *(const float4*)(b1 + cl * 8);
    float4 b4 = *(const float4*)(b1 + cl * 8 + 4);
    float bb[8] = {b0.x, b0.y, b0.z, b0.w, b4.x, b4.y, b4.z, b4.w};
    us8 o;
    #pragma unroll
    for (int k = 0; k < 8; k++)
      o[k] = f2bf(fmaxf(acc[k] * di + bf2f(rv[k]) + bb[k], 0.f));
    *(us8*)(h + (size_t)n * 256 + cl * 8) = o;
  }
}

// ---------------- Aggregation 2 + classifier + log_softmax (fused, bf16) ----------------

__global__ void k_agg2cls(const unsigned short* __restrict__ C2,
                          const float* __restrict__ b2,
                          const float* __restrict__ Wc,
                          const float* __restrict__ bc,
                          const int* __restrict__ offs, const int* __restrict__ cnt,
                          const float* __restrict__ deginv,
                          const int* __restrict__ csr,
                          float* __restrict__ out, int N)
{
  int wv = threadIdx.x >> 6, lane = threadIdx.x & 63;
  int n = blockIdx.x * 4 + wv;
  if (n >= N) return;
  int beg = offs[n], d = cnt[n];
  const int g = lane >> 4;       // edge-group 0..3
  const int cl = lane & 15;      // cols cl*8..cl*8+7

  float acc[8];
  #pragma unroll
  for (int k = 0; k < 8; k++) acc[k] = 0.f;

  for (int w0 = 0; w0 < d; w0 += 64){
    int wlen = min(d - w0, 64);
    int idx = 0;
    if (lane < wlen) idx = csr[beg + w0 + lane];
    int nIter = (wlen + 31) >> 5;              // uniform across the wave
    for (int t = 0; t < nIter; t++){
      int e0 = t * 32 + g;
      int s0 = __shfl(idx, e0);
      int s1 = __shfl(idx, e0 + 4);
      int s2 = __shfl(idx, e0 + 8);
      int s3 = __shfl(idx, e0 + 12);
      int s4 = __shfl(idx, e0 + 16);
      int s5 = __shfl(idx, e0 + 20);
      int s6 = __shfl(idx, e0 + 24);
      int s7 = __shfl(idx, e0 + 28);
      us8 v0 = *(const us8*)(C2 + (size_t)s0 * 256 + cl * 8);
      us8 v1 = *(const us8*)(C2 + (size_t)s1 * 256 + cl * 8);
      us8 v2 = *(const us8*)(C2 + (size_t)s2 * 256 + cl * 8);
      us8 v3 = *(const us8*)(C2 + (size_t)s3 * 256 + cl * 8);
      us8 v4 = *(const us8*)(C2 + (size_t)s4 * 256 + cl * 8);
      us8 v5 = *(const us8*)(C2 + (size_t)s5 * 256 + cl * 8);
      us8 v6 = *(const us8*)(C2 + (size_t)s6 * 256 + cl * 8);
      us8 v7 = *(const us8*)(C2 + (size_t)s7 * 256 + cl * 8);
      if (e0 < wlen)      addv(acc, v0);
      if (e0 + 4 < wlen)  addv(acc, v1);
      if (e0 + 8 < wlen)  addv(acc, v2);
      if (e0 + 12 < wlen) addv(acc, v3);
      if (e0 + 16 < wlen) addv(acc, v4);
      if (e0 + 20 < wlen) addv(acc, v5);
      if (e0 + 24 < wlen) addv(acc, v6);
      if (e0 + 28 < wlen) addv(acc, v7);
    }
  }
  #pragma unroll
  for (int k = 0; k < 8; k++){
    acc[k] += __shfl_xor(acc[k], 16);
    acc[k] += __shfl_xor(acc[k], 32);
  }

  float di = deginv[n];
  us8 rv = *(const us8*)(C2 + (size_t)n * 256 + 128 + cl * 8);
  float4 b0 = *(const float4*)(b2 + cl * 8);
  float4 b4 = *(const float4*)(b2 + cl * 8 + 4);
  float bb[8] = {b0.x, b0.y, b0.z, b0.w, b4.x, b4.y, b4.z, b4.w};
  float p0 = 0.f, p1 = 0.f;
  #pragma unroll
  for (int k = 0; k < 8; k += 2){
    float h0 = fmaxf(acc[k]     * di + bf2f(rv[k])     + bb[k],     0.f);
    float h1 = fmaxf(acc[k + 1] * di + bf2f(rv[k + 1]) + bb[k + 1], 0.f);
    float4 w = *(const float4*)(Wc + (cl * 8 + k) * 2);
    p0 += h0 * w.x + h1 * w.z;
    p1 += h0 * w.y + h1 * w.w;
  }
  #pragma unroll
  for (int off = 8; off; off >>= 1){
    p0 += __shfl_xor(p0, off);
    p1 += __shfl_xor(p1, off);
  }
  if (lane == 0){
    float z0 = p0 + bc[0], z1 = p1 + bc[1];
    float m = fmaxf(z0, z1);
    float lse = m + logf(expf(z0 - m) + expf(z1 - m));
    out[(size_t)n * 2 + 0] = z0 - lse;
    out[(size_t)n * 2 + 1] = z1 - lse;
  }
}

// ---------------- host launch ----------------

extern "C" void kernel_launch(void* const* d_in, const int* in_sizes, int n_in,
                              void* d_out, int out_size, void* d_ws, size_t ws_size,
                              hipStream_t stream)
{
  const float* x   = (const float*)d_in[0];
  const int*   ei  = (const int*)d_in[1];
  const float* W1l = (const float*)d_in[2];
  const float* W1r = (const float*)d_in[3];
  const float* b1  = (const float*)d_in[4];
  const float* W2l = (const float*)d_in[5];
  const float* W2r = (const float*)d_in[6];
  const float* b2  = (const float*)d_in[7];
  const float* Wc  = (const float*)d_in[8];
  const float* bc  = (const float*)d_in[9];
  float* out = (float*)d_out;

  const int N = NN, E = NE;
  const int* src = ei;
  const int* dst = ei + E;

  char* ws = (char*)d_ws;
  size_t off = 0;
  auto alloc = [&](size_t bytes) -> void* {
    void* p = ws + off;
    off += (bytes + 255) & ~(size_t)255;
    return p;
  };
  int*   cnt      = (int*)alloc((size_t)N * 4);
  int*   offs     = (int*)alloc((size_t)N * 4);
  int*   cursor   = (int*)alloc((size_t)N * 4);
  float* deginv   = (float*)alloc((size_t)N * 4);
  int*   partials = (int*)alloc(1024);
  int*   csr      = (int*)alloc((size_t)E * 4);
  unsigned short* Bt1 = (unsigned short*)alloc((size_t)512 * 256 * 2);
  unsigned short* Bt2 = (unsigned short*)alloc((size_t)256 * 256 * 2);
  unsigned short* xb  = (unsigned short*)alloc((size_t)MPAD * 256 * 2);
  unsigned char*  Q8  = (unsigned char*)alloc((size_t)MPAD * 256);
  unsigned short* R1  = (unsigned short*)alloc((size_t)MPAD * 256 * 2);

  unsigned short* h  = xb;   // alias: xb dead after gemm1
  unsigned short* C2 = R1;   // alias: R1 dead after agg1

  (void)in_sizes; (void)n_in; (void)out_size; (void)ws_size;

  hipMemsetAsync(cnt, 0, (size_t)N * 4, stream);

  int nchunk = (N + 1023) / 1024;
  k_degree<<<(E + 255) / 256, 256, 0, stream>>>(dst, cnt, E);
  k_chunk_sum<<<nchunk, 1024, 0, stream>>>(cnt, partials, N);
  k_chunk_scan<<<nchunk, 1024, 0, stream>>>(cnt, partials, nchunk, offs, cursor, deginv, N);
  k_fill<<<(E + 255) / 256, 256, 0, stream>>>(src, dst, cursor, csr, E);

  k_cvt<<<MPAD / 8, 256, 0, stream>>>(x, xb);
  k_prep_w<<<512, 256, 0, stream>>>(W1l, W1r, W2l, W2r, Bt1, Bt2);

  // layer 1: [q1|r1] = xb @ [W1l|W1r]; q1 -> Q8 fp8, r1 -> R1 bf16
  // single-wave 64x64 tiles: grid = MTP64 * 8 n-tiles, block = 64
  k_gemm<3, true><<<MTP64 * 8, 64, 0, stream>>>(xb, Bt1, R1, Q8);
  k_agg1<<<N / 4, 256, 0, stream>>>(Q8, R1, b1, offs, cnt, deginv, csr, h, N);

  // layer 2: C2 = h @ [W2l|W2r]; grid = MTP64 * 4 n-tiles
  k_gemm<2, false><<<MTP64 * 4, 64, 0, stream>>>(h, Bt2, C2, (unsigned char*)nullptr);
  // agg2 + classifier + log_softmax fused
  k_agg2cls<<<N / 4, 256, 0, stream>>>(C2, b2, Wc, bc, offs, cnt, deginv, csr, out, N);
}

// Round 12
// 303.045 us; speedup vs baseline: 1.2963x; 1.1515x over previous
//
#include <hip/hip_runtime.h>
#include <hip/hip_bf16.h>

#define NN 100000
#define NE 1000000
#define MPAD 100096   // 1564*64
#define MT64  1564    // 64-row m-tiles
#define MTP64 1568    // padded (8*196)
#define NG1   (MTP64 * 8)        // 12544 gemm1 tile-blocks
#define NFB   (NE / 64)          // 15625 fill blocks (64 edges each)
#define NDB   ((NE + 255) / 256) // 3907 degree blocks
#define NCB   (MPAD / 8)         // 12512 cvt blocks

typedef __attribute__((ext_vector_type(8))) short bf16x8;
typedef __attribute__((ext_vector_type(4))) float f32x4;
typedef __attribute__((ext_vector_type(2))) float f32x2;
typedef __attribute__((ext_vector_type(8))) unsigned short us8;

static __device__ __forceinline__ float bf2f(unsigned short u){
  unsigned int x = ((unsigned int)u) << 16;
  return __uint_as_float(x);
}
static __device__ __forceinline__ unsigned short f2bf(float f){
  unsigned int x = __float_as_uint(f);
  unsigned int r = (x + 0x7fffu + ((x >> 16) & 1u)) >> 16;
  return (unsigned short)r;
}
static __device__ __forceinline__ void addv(float* acc, us8 v){
  #pragma unroll
  for (int k = 0; k < 8; k++) acc[k] += bf2f(v[k]);
}
// fp8 e4m3fn encode: RNE, saturate 448, denormals handled
static __device__ __forceinline__ unsigned char f2fp8(float f){
  unsigned int u = __float_as_uint(f);
  unsigned int s = (u >> 24) & 0x80u;
  float av = fabsf(f);
  if (av >= 448.f) return (unsigned char)(s | 0x7Eu);
  if (av < 0.015625f){
    int m = (int)(av * 512.0f + 0.5f);
    return (unsigned char)(s | (unsigned)m);
  }
  unsigned int au = u & 0x7FFFFFFFu;
  unsigned int r = au + 0x7FFFFu + ((au >> 20) & 1u);
  return (unsigned char)(s | ((r >> 20) - 960u));
}
#if !__has_builtin(__builtin_amdgcn_cvt_pk_f32_fp8)
static __device__ __forceinline__ float fp8tof(unsigned char b){
  unsigned int s = ((unsigned int)(b & 0x80u)) << 24;
  unsigned int e = (b >> 3) & 0xFu, m = b & 7u;
  float v = (e == 0) ? ((float)m * 0.001953125f)
                     : __uint_as_float(((e + 120u) << 23) | (m << 20));
  return __uint_as_float(__float_as_uint(v) | s);
}
#endif
static __device__ __forceinline__ void addq(float* acc, uint2 v){
#if __has_builtin(__builtin_amdgcn_cvt_pk_f32_fp8)
  f32x2 p0 = __builtin_amdgcn_cvt_pk_f32_fp8((int)v.x, false);
  f32x2 p1 = __builtin_amdgcn_cvt_pk_f32_fp8((int)v.x, true);
  f32x2 p2 = __builtin_amdgcn_cvt_pk_f32_fp8((int)v.y, false);
  f32x2 p3 = __builtin_amdgcn_cvt_pk_f32_fp8((int)v.y, true);
  acc[0] += p0[0]; acc[1] += p0[1]; acc[2] += p1[0]; acc[3] += p1[1];
  acc[4] += p2[0]; acc[5] += p2[1]; acc[6] += p3[0]; acc[7] += p3[1];
#else
  unsigned int a = v.x, b = v.y;
  acc[0] += fp8tof(a & 0xFF);         acc[1] += fp8tof((a >> 8) & 0xFF);
  acc[2] += fp8tof((a >> 16) & 0xFF); acc[3] += fp8tof(a >> 24);
  acc[4] += fp8tof(b & 0xFF);         acc[5] += fp8tof((b >> 8) & 0xFF);
  acc[6] += fp8tof((b >> 16) & 0xFF); acc[7] += fp8tof(b >> 24);
#endif
}
static __device__ __forceinline__ void gld16(const void* g, void* l){
  __builtin_amdgcn_global_load_lds((const __attribute__((address_space(1))) void*)g,
                                   (__attribute__((address_space(3))) void*)l, 16, 0, 0);
}

// ---------------- Fused: degree || cvt || prep_w (all independent) ----------------

__global__ __launch_bounds__(256)
void k_dc(const int* __restrict__ dst, int* __restrict__ cnt,
          const float* __restrict__ x, unsigned short* __restrict__ xb,
          const float* __restrict__ W1l, const float* __restrict__ W1r,
          const float* __restrict__ W2l, const float* __restrict__ W2r,
          unsigned short* __restrict__ Bt1, unsigned short* __restrict__ Bt2)
{
  const int bid = blockIdx.x, t = threadIdx.x;
  int role, idx;
  if (bid < 2 * NDB){
    role = bid & 1;               // 1=degree, 0=cvt (interleaved -> concurrent)
    idx = bid >> 1;
  } else if (bid < NDB + NCB){
    role = 0; idx = bid - NDB;
  } else {
    role = 2; idx = bid - NDB - NCB;
  }

  if (role == 1){
    int e = idx * 256 + t;
    if (e < NE) atomicAdd(&cnt[dst[e]], 1);
  } else if (role == 0){
    size_t i = ((size_t)idx * 256 + t) * 8;
    if (i >= (size_t)MPAD * 256) return;
    int row = (int)(i >> 8);
    us8 o;
    if (row < NN){
      const float4* p = (const float4*)(x + i);
      float4 a = p[0], b = p[1];
      o[0]=f2bf(a.x); o[1]=f2bf(a.y); o[2]=f2bf(a.z); o[3]=f2bf(a.w);
      o[4]=f2bf(b.x); o[5]=f2bf(b.y); o[6]=f2bf(b.z); o[7]=f2bf(b.w);
    } else {
      #pragma unroll
      for (int j = 0; j < 8; j++) o[j] = 0;
    }
    *(us8*)(xb + i) = o;
  } else {
    int i = idx * 256 + t;
    if (i < 512 * 256){
      int n = i >> 8, k = i & 255;
      float v = (n < 256) ? W1l[k * 256 + n] : W1r[k * 256 + (n - 256)];
      Bt1[n * 256 + k] = f2bf(v);
    }
    if (i < 256 * 256){
      int n = i >> 8, k = i & 255;
      float v = (n < 128) ? W2l[k * 128 + n] : W2r[k * 128 + (n - 128)];
      Bt2[n * 256 + k] = f2bf(v);
    }
  }
}

// ---------------- CSR scan kernels ----------------

__global__ void k_chunk_sum(const int* __restrict__ cnt, int* __restrict__ partials, int N){
  __shared__ int sw[16];
  int b = blockIdx.x, t = threadIdx.x;
  int i = b * 1024 + t;
  int v = (i < N) ? cnt[i] : 0;
  #pragma unroll
  for (int off = 32; off; off >>= 1) v += __shfl_xor(v, off);
  int lane = t & 63, w = t >> 6;
  if (lane == 0) sw[w] = v;
  __syncthreads();
  if (t < 16){
    int s = sw[t];
    #pragma unroll
    for (int off = 8; off; off >>= 1) s += __shfl_xor(s, off);
    if (t == 0) partials[b] = s;
  }
}

__global__ void k_chunk_scan(const int* __restrict__ cnt, const int* __restrict__ partials,
                             int nchunk,
                             int* __restrict__ offs, int* __restrict__ cursor,
                             float* __restrict__ deginv, int N){
  __shared__ int sd[1024];
  __shared__ int sp[128];
  int b = blockIdx.x, t = threadIdx.x;
  if (t < 128) sp[t] = (t < b && t < nchunk) ? partials[t] : 0;
  int i = b * 1024 + t;
  int v = (i < N) ? cnt[i] : 0;
  sd[t] = v;
  __syncthreads();
  #pragma unroll
  for (int off = 64; off; off >>= 1){
    if (t < off) sp[t] += sp[t + off];
    __syncthreads();
  }
  for (int off = 1; off < 1024; off <<= 1){
    int x = (t >= off) ? sd[t - off] : 0;
    __syncthreads();
    sd[t] += x;
    __syncthreads();
  }
  if (i < N){
    int excl = sp[0] + sd[t] - v;
    offs[i] = excl;
    cursor[i] = excl;
    deginv[i] = (v > 0) ? (1.0f / (float)v) : 0.0f;
  }
}

// ---------------- Fused: CSR fill || GEMM layer 1 (independent stages) ----------------
// 64-thread blocks. Interleave mod 16 (8 gemm + 8 fill) so gemm idx = bid (mod 8)
// -> XCD pinning preserved. Fill path ignores the LDS.
// gemm: single-wave 64x64 tile, barrier-free (s_waitcnt only). SPLIT epilogue:
// cols<256 -> Q8 fp8 [MPAD][256], cols>=256 -> R1 bf16 [MPAD][256].

__global__ __launch_bounds__(64)
void k_fg(const unsigned short* __restrict__ A,
          const unsigned short* __restrict__ Bt,
          unsigned short* __restrict__ R1,
          unsigned char* __restrict__ Q8,
          const int* __restrict__ src, const int* __restrict__ dst,
          int* __restrict__ cursor, int* __restrict__ csr)
{
  __shared__ __align__(16) unsigned short lA[64 * 64];  // 8KB
  __shared__ __align__(16) unsigned short lB[64 * 64];  // 8KB
  const int bid = blockIdx.x;
  const int lane = threadIdx.x & 63;

  bool isg; int idx;
  if (bid < 2 * NG1){
    isg = (bid & 15) < 8;
    idx = ((bid >> 4) << 3) + (bid & 7);
  } else {
    isg = false; idx = bid - NG1;
  }

  if (!isg){
    int e = idx * 64 + lane;
    if (e < NE){
      int p = atomicAdd(&cursor[dst[e]], 1);
      csr[p] = src[e];
    }
    return;
  }

  // ---- gemm1 tile idx ----
  const int xcd = idx & 7, j = idx >> 3;
  const int mt  = xcd * (MTP64 / 8) + (j >> 3);
  if (mt >= MT64) return;
  const int nt  = j & 7;
  const int m0  = mt * 64;
  const int n0  = nt * 64;

  f32x4 acc[4][4] = {};
  const int srow = lane >> 3;
  const int sc   = (lane & 7) ^ ((lane >> 3) & 7);

  for (int kt = 0; kt < 4; ++kt){
    asm volatile("s_waitcnt lgkmcnt(0)" ::: "memory");
    #pragma unroll
    for (int s = 0; s < 8; ++s){
      int row = s * 8 + srow;
      gld16(A  + (size_t)(m0 + row) * 256 + kt * 64 + sc * 8, &lA[s * 512]);
      gld16(Bt + (size_t)(n0 + row) * 256 + kt * 64 + sc * 8, &lB[s * 512]);
    }
    asm volatile("s_waitcnt vmcnt(0)" ::: "memory");
    __builtin_amdgcn_sched_barrier(0);
    #pragma unroll
    for (int ks = 0; ks < 2; ++ks){
      bf16x8 av[4], bv[4];
      const int kc = ks * 4 + (lane >> 4);
      #pragma unroll
      for (int m = 0; m < 4; m++){
        int r = m * 16 + (lane & 15);
        av[m] = *(const bf16x8*)&lA[r * 64 + ((kc ^ (r & 7)) << 3)];
      }
      #pragma unroll
      for (int n = 0; n < 4; n++){
        int c = n * 16 + (lane & 15);
        bv[n] = *(const bf16x8*)&lB[c * 64 + ((kc ^ (c & 7)) << 3)];
      }
      #pragma unroll
      for (int m = 0; m < 4; m++)
        #pragma unroll
        for (int n = 0; n < 4; n++)
          acc[m][n] = __builtin_amdgcn_mfma_f32_16x16x32_bf16(av[m], bv[n], acc[m][n], 0, 0, 0);
    }
  }

  const int crow0 = m0 + (lane >> 4) * 4;
  const int ccol0 = n0 + (lane & 15);
  if (n0 < 256){
    #pragma unroll
    for (int m = 0; m < 4; m++){
      #pragma unroll
      for (int r = 0; r < 4; r++){
        size_t rowoff = (size_t)(crow0 + m * 16 + r) * 256;
        #pragma unroll
        for (int n = 0; n < 4; n++)
          Q8[rowoff + ccol0 + n * 16] = f2fp8(acc[m][n][r]);
      }
    }
  } else {
    const int cbase = ccol0 - 256;
    #pragma unroll
    for (int m = 0; m < 4; m++){
      #pragma unroll
      for (int r = 0; r < 4; r++){
        size_t rowoff = (size_t)(crow0 + m * 16 + r) * 256;
        #pragma unroll
        for (int n = 0; n < 4; n++)
          R1[rowoff + cbase + n * 16] = f2bf(acc[m][n][r]);
      }
    }
  }
}

// ---------------- GEMM layer 2 (single-wave, barrier-free) ----------------

template<int NTL2>
__global__ __launch_bounds__(64)
void k_gemm(const unsigned short* __restrict__ A,
            const unsigned short* __restrict__ Bt,
            unsigned short* __restrict__ C)
{
  const int bid = blockIdx.x;
  const int xcd = bid & 7, j = bid >> 3;
  const int mt  = xcd * (MTP64 / 8) + (j >> NTL2);
  if (mt >= MT64) return;
  const int nt  = j & ((1 << NTL2) - 1);
  const int m0  = mt * 64;
  const int n0  = nt * 64;
  const int Nout = 64 << NTL2;

  __shared__ __align__(16) unsigned short lA[64 * 64];
  __shared__ __align__(16) unsigned short lB[64 * 64];
  const int lane = threadIdx.x & 63;

  f32x4 acc[4][4] = {};
  const int srow = lane >> 3;
  const int sc   = (lane & 7) ^ ((lane >> 3) & 7);

  for (int kt = 0; kt < 4; ++kt){
    asm volatile("s_waitcnt lgkmcnt(0)" ::: "memory");
    #pragma unroll
    for (int s = 0; s < 8; ++s){
      int row = s * 8 + srow;
      gld16(A  + (size_t)(m0 + row) * 256 + kt * 64 + sc * 8, &lA[s * 512]);
      gld16(Bt + (size_t)(n0 + row) * 256 + kt * 64 + sc * 8, &lB[s * 512]);
    }
    asm volatile("s_waitcnt vmcnt(0)" ::: "memory");
    __builtin_amdgcn_sched_barrier(0);
    #pragma unroll
    for (int ks = 0; ks < 2; ++ks){
      bf16x8 av[4], bv[4];
      const int kc = ks * 4 + (lane >> 4);
      #pragma unroll
      for (int m = 0; m < 4; m++){
        int r = m * 16 + (lane & 15);
        av[m] = *(const bf16x8*)&lA[r * 64 + ((kc ^ (r & 7)) << 3)];
      }
      #pragma unroll
      for (int n = 0; n < 4; n++){
        int c = n * 16 + (lane & 15);
        bv[n] = *(const bf16x8*)&lB[c * 64 + ((kc ^ (c & 7)) << 3)];
      }
      #pragma unroll
      for (int m = 0; m < 4; m++)
        #pragma unroll
        for (int n = 0; n < 4; n++)
          acc[m][n] = __builtin_amdgcn_mfma_f32_16x16x32_bf16(av[m], bv[n], acc[m][n], 0, 0, 0);
    }
  }

  const int crow0 = m0 + (lane >> 4) * 4;
  const int ccol0 = n0 + (lane & 15);
  #pragma unroll
  for (int m = 0; m < 4; m++){
    #pragma unroll
    for (int r = 0; r < 4; r++){
      size_t rowoff = (size_t)(crow0 + m * 16 + r) * Nout;
      #pragma unroll
      for (int n = 0; n < 4; n++)
        C[rowoff + ccol0 + n * 16] = f2bf(acc[m][n][r]);
    }
  }
}

// ---------------- Aggregation 1: h = relu(deginv*agg(q1_fp8) + r1 + b1) ----------------

__global__ void k_agg1(const unsigned char* __restrict__ Q8,
                       const unsigned short* __restrict__ R1,
                       const float* __restrict__ b1,
                       const int* __restrict__ offs, const int* __restrict__ cnt,
                       const float* __restrict__ deginv,
                       const int* __restrict__ csr,
                       unsigned short* __restrict__ h, int N)
{
  int wv = threadIdx.x >> 6, lane = threadIdx.x & 63;
  int n = blockIdx.x * 4 + wv;
  if (n >= N) return;
  int beg = offs[n], d = cnt[n];
  const int g = lane >> 5;
  const int cl = lane & 31;
  const unsigned char* Qb = Q8 + cl * 8;

  float acc[8];
  #pragma unroll
  for (int k = 0; k < 8; k++) acc[k] = 0.f;

  for (int w0 = 0; w0 < d; w0 += 64){
    int wlen = min(d - w0, 64);
    int idx = 0;
    if (lane < wlen) idx = csr[beg + w0 + lane];
    int nIter = (wlen + 15) >> 4;
    for (int t = 0; t < nIter; t++){
      int e0 = t * 16 + g;
      int s0 = __shfl(idx, e0);
      int s1 = __shfl(idx, e0 + 2);
      int s2 = __shfl(idx, e0 + 4);
      int s3 = __shfl(idx, e0 + 6);
      int s4 = __shfl(idx, e0 + 8);
      int s5 = __shfl(idx, e0 + 10);
      int s6 = __shfl(idx, e0 + 12);
      int s7 = __shfl(idx, e0 + 14);
      uint2 v0 = *(const uint2*)(Qb + (size_t)s0 * 256);
      uint2 v1 = *(const uint2*)(Qb + (size_t)s1 * 256);
      uint2 v2 = *(const uint2*)(Qb + (size_t)s2 * 256);
      uint2 v3 = *(const uint2*)(Qb + (size_t)s3 * 256);
      uint2 v4 = *(const uint2*)(Qb + (size_t)s4 * 256);
      uint2 v5 = *(const uint2*)(Qb + (size_t)s5 * 256);
      uint2 v6 = *(const uint2*)(Qb + (size_t)s6 * 256);
      uint2 v7 = *(const uint2*)(Qb + (size_t)s7 * 256);
      if (e0 < wlen)      addq(acc, v0);
      if (e0 + 2 < wlen)  addq(acc, v1);
      if (e0 + 4 < wlen)  addq(acc, v2);
      if (e0 + 6 < wlen)  addq(acc, v3);
      if (e0 + 8 < wlen)  addq(acc, v4);
      if (e0 + 10 < wlen) addq(acc, v5);
      if (e0 + 12 < wlen) addq(acc, v6);
      if (e0 + 14 < wlen) addq(acc, v7);
    }
  }
  #pragma unroll
  for (int k = 0; k < 8; k++) acc[k] += __shfl_xor(acc[k], 32);

  if (lane < 32){
    float di = deginv[n];
    us8 rv = *(const us8*)(R1 + (size_t)n * 256 + cl * 8);
    float4 b0 = *(const float4*)(b1 + cl * 8);
    float4 b4 = *(const float4*)(b1 + cl * 8 + 4);
    float bb[8] = {b0.x, b0.y, b0.z, b0.w, b4.x, b4.y, b4.z, b4.w};
    us8 o;
    #pragma unroll
    for (int k = 0; k < 8; k++)
      o[k] = f2bf(fmaxf(acc[k] * di + bf2f(rv[k]) + bb[k], 0.f));
    *(us8*)(h + (size_t)n * 256 + cl * 8) = o;
  }
}

// ---------------- Aggregation 2 + classifier + log_softmax (fused, bf16) ----------------

__global__ void k_agg2cls(const unsigned short* __restrict__ C2,
                          const float* __restrict__ b2,
                          const float* __restrict__ Wc,
                          const float* __restrict__ bc,
                          const int* __restrict__ offs, const int* __restrict__ cnt,
                          const float* __restrict__ deginv,
                          const int* __restrict__ csr,
                          float* __restrict__ out, int N)
{
  int wv = threadIdx.x >> 6, lane = threadIdx.x & 63;
  int n = blockIdx.x * 4 + wv;
  if (n >= N) return;
  int beg = offs[n], d = cnt[n];
  const int g = lane >> 4;
  const int cl = lane & 15;

  float acc[8];
  #pragma unroll
  for (int k = 0; k < 8; k++) acc[k] = 0.f;

  for (int w0 = 0; w0 < d; w0 += 64){
    int wlen = min(d - w0, 64);
    int idx = 0;
    if (lane < wlen) idx = csr[beg + w0 + lane];
    int nIter = (wlen + 31) >> 5;
    for (int t = 0; t < nIter; t++){
      int e0 = t * 32 + g;
      int s0 = __shfl(idx, e0);
      int s1 = __shfl(idx, e0 + 4);
      int s2 = __shfl(idx, e0 + 8);
      int s3 = __shfl(idx, e0 + 12);
      int s4 = __shfl(idx, e0 + 16);
      int s5 = __shfl(idx, e0 + 20);
      int s6 = __shfl(idx, e0 + 24);
      int s7 = __shfl(idx, e0 + 28);
      us8 v0 = *(const us8*)(C2 + (size_t)s0 * 256 + cl * 8);
      us8 v1 = *(const us8*)(C2 + (size_t)s1 * 256 + cl * 8);
      us8 v2 = *(const us8*)(C2 + (size_t)s2 * 256 + cl * 8);
      us8 v3 = *(const us8*)(C2 + (size_t)s3 * 256 + cl * 8);
      us8 v4 = *(const us8*)(C2 + (size_t)s4 * 256 + cl * 8);
      us8 v5 = *(const us8*)(C2 + (size_t)s5 * 256 + cl * 8);
      us8 v6 = *(const us8*)(C2 + (size_t)s6 * 256 + cl * 8);
      us8 v7 = *(const us8*)(C2 + (size_t)s7 * 256 + cl * 8);
      if (e0 < wlen)      addv(acc, v0);
      if (e0 + 4 < wlen)  addv(acc, v1);
      if (e0 + 8 < wlen)  addv(acc, v2);
      if (e0 + 12 < wlen) addv(acc, v3);
      if (e0 + 16 < wlen) addv(acc, v4);
      if (e0 + 20 < wlen) addv(acc, v5);
      if (e0 + 24 < wlen) addv(acc, v6);
      if (e0 + 28 < wlen) addv(acc, v7);
    }
  }
  #pragma unroll
  for (int k = 0; k < 8; k++){
    acc[k] += __shfl_xor(acc[k], 16);
    acc[k] += __shfl_xor(acc[k], 32);
  }

  float di = deginv[n];
  us8 rv = *(const us8*)(C2 + (size_t)n * 256 + 128 + cl * 8);
  float4 b0 = *(const float4*)(b2 + cl * 8);
  float4 b4 = *(const float4*)(b2 + cl * 8 + 4);
  float bb[8] = {b0.x, b0.y, b0.z, b0.w, b4.x, b4.y, b4.z, b4.w};
  float p0 = 0.f, p1 = 0.f;
  #pragma unroll
  for (int k = 0; k < 8; k += 2){
    float h0 = fmaxf(acc[k]     * di + bf2f(rv[k])     + bb[k],     0.f);
    float h1 = fmaxf(acc[k + 1] * di + bf2f(rv[k + 1]) + bb[k + 1], 0.f);
    float4 w = *(const float4*)(Wc + (cl * 8 + k) * 2);
    p0 += h0 * w.x + h1 * w.z;
    p1 += h0 * w.y + h1 * w.w;
  }
  #pragma unroll
  for (int off = 8; off; off >>= 1){
    p0 += __shfl_xor(p0, off);
    p1 += __shfl_xor(p1, off);
  }
  if (lane == 0){
    float z0 = p0 + bc[0], z1 = p1 + bc[1];
    float m = fmaxf(z0, z1);
    float lse = m + logf(expf(z0 - m) + expf(z1 - m));
    out[(size_t)n * 2 + 0] = z0 - lse;
    out[(size_t)n * 2 + 1] = z1 - lse;
  }
}

// ---------------- host launch ----------------

extern "C" void kernel_launch(void* const* d_in, const int* in_sizes, int n_in,
                              void* d_out, int out_size, void* d_ws, size_t ws_size,
                              hipStream_t stream)
{
  const float* x   = (const float*)d_in[0];
  const int*   ei  = (const int*)d_in[1];
  const float* W1l = (const float*)d_in[2];
  const float* W1r = (const float*)d_in[3];
  const float* b1  = (const float*)d_in[4];
  const float* W2l = (const float*)d_in[5];
  const float* W2r = (const float*)d_in[6];
  const float* b2  = (const float*)d_in[7];
  const float* Wc  = (const float*)d_in[8];
  const float* bc  = (const float*)d_in[9];
  float* out = (float*)d_out;

  const int N = NN, E = NE;
  const int* src = ei;
  const int* dst = ei + E;

  char* ws = (char*)d_ws;
  size_t off = 0;
  auto alloc = [&](size_t bytes) -> void* {
    void* p = ws + off;
    off += (bytes + 255) & ~(size_t)255;
    return p;
  };
  int*   cnt      = (int*)alloc((size_t)N * 4);
  int*   offs     = (int*)alloc((size_t)N * 4);
  int*   cursor   = (int*)alloc((size_t)N * 4);
  float* deginv   = (float*)alloc((size_t)N * 4);
  int*   partials = (int*)alloc(1024);
  int*   csr      = (int*)alloc((size_t)E * 4);
  unsigned short* Bt1 = (unsigned short*)alloc((size_t)512 * 256 * 2);
  unsigned short* Bt2 = (unsigned short*)alloc((size_t)256 * 256 * 2);
  unsigned short* xb  = (unsigned short*)alloc((size_t)MPAD * 256 * 2);
  unsigned char*  Q8  = (unsigned char*)alloc((size_t)MPAD * 256);
  unsigned short* R1  = (unsigned short*)alloc((size_t)MPAD * 256 * 2);

  unsigned short* h  = xb;   // alias: xb dead after gemm1
  unsigned short* C2 = R1;   // alias: R1 dead after agg1

  (void)in_sizes; (void)n_in; (void)out_size; (void)ws_size;

  hipMemsetAsync(cnt, 0, (size_t)N * 4, stream);

  // degree || cvt || prep_w (one fused launch; independent roles interleaved)
  k_dc<<<NDB + NCB + 512, 256, 0, stream>>>(dst, cnt, x, xb, W1l, W1r, W2l, W2r, Bt1, Bt2);

  int nchunk = (N + 1023) / 1024;
  k_chunk_sum<<<nchunk, 1024, 0, stream>>>(cnt, partials, N);
  k_chunk_scan<<<nchunk, 1024, 0, stream>>>(cnt, partials, nchunk, offs, cursor, deginv, N);

  // CSR fill || GEMM layer 1 (fused; both independent, overlap write-drain with MFMA)
  k_fg<<<NG1 + NFB, 64, 0, stream>>>(xb, Bt1, R1, Q8, src, dst, cursor, csr);

  k_agg1<<<N / 4, 256, 0, stream>>>(Q8, R1, b1, offs, cnt, deginv, csr, h, N);

  // layer 2: C2 = h @ [W2l|W2r]
  k_gemm<2><<<MTP64 * 4, 64, 0, stream>>>(h, Bt2, C2);
  k_agg2cls<<<N / 4, 256, 0, stream>>>(C2, b2, Wc, bc, offs, cnt, deginv, csr, out, N);
}